// Round 10
// baseline (166.745 us; speedup 1.0000x reference)
//
#include <hip/hip_runtime.h>
#include <hip/hip_fp16.h>
#include <math.h>

#define BB 32
#define TT 256
#define DD 1024
#define NNODES 2048
#define EE 65536
#define LN_EPS 1e-5f

typedef _Float16 halfx8 __attribute__((ext_vector_type(8)));
typedef __attribute__((ext_vector_type(4))) float floatx4;

__device__ __forceinline__ float gelu_fast(float x) {
    // tanh-approx gelu: x - x/(1+exp2(x*(2.302118 + 0.102945*x^2)))
    float x2 = x * x;
    float z = x * fmaf(0.10294456f, x2, 2.30211786f);
    float e = __builtin_amdgcn_exp2f(z);
    float r = __builtin_amdgcn_rcpf(1.0f + e);
    return fmaf(-x, r, x);
}

// packed half2 sigmoid-gelu: x / (1 + exp2(-2.4554669 x))
__device__ __forceinline__ __half2 gelu_h2(__half2 x) {
    const __half2 k = __float2half2_rn(-2.4554669f);
    const __half2 one = __float2half2_rn(1.0f);
    __half2 e = h2exp2(__hmul2(x, k));
    return __hmul2(x, h2rcp(__hadd2(e, one)));
}

__device__ __forceinline__ float dot2f(__half2 a, __half2 b, float c) {
#if __has_builtin(__builtin_amdgcn_fdot2)
    typedef _Float16 v2h __attribute__((ext_vector_type(2)));
    return __builtin_amdgcn_fdot2(*(v2h*)&a, *(v2h*)&b, c, false);
#else
    float2 af = __half22float2(a), bf = __half22float2(b);
    return fmaf(af.x, bf.x, fmaf(af.y, bf.y, c));
#endif
}

__device__ __forceinline__ unsigned short f32_to_h16(float f) {
    return __half_as_ushort(__float2half_rn(f));
}

__device__ __forceinline__ void load_lds16(const void* g, void* l) {
    __builtin_amdgcn_global_load_lds(
        (const __attribute__((address_space(1))) void*)g,
        (__attribute__((address_space(3))) void*)l, 16, 0, 0);
}

// ---------------- K1: zero d_out + LayerNorm (blocks 0..31) + prep (32..4127)
__global__ __launch_bounds__(256) void k1_zero_ln_prep_kernel(
    const float* __restrict__ x, const float* __restrict__ g,
    const float* __restrict__ bta, const float* __restrict__ Wf1,
    float* __restrict__ hnorm, float* __restrict__ out,
    unsigned short* __restrict__ nodesH, unsigned short* __restrict__ Wf1T) {
    __shared__ float smem[32 * 33];
    int t = threadIdx.x;
    int b = blockIdx.x;
    if (b < BB) {
        int zi = b * 256 + t;
        if (zi < BB + NNODES * 3) out[zi] = 0.0f;
        float* red = smem;
        const float* row = x + (size_t)b * TT * DD;
        float v[4];
        float s = 0.0f;
        #pragma unroll
        for (int j = 0; j < 4; ++j) { v[j] = row[t + j * 256]; s += v[j]; }
        red[t] = s; __syncthreads();
        for (int off = 128; off > 0; off >>= 1) {
            if (t < off) red[t] += red[t + off];
            __syncthreads();
        }
        float mu = red[0] * (1.0f / DD);
        __syncthreads();
        float sq = 0.0f;
        #pragma unroll
        for (int j = 0; j < 4; ++j) { float d = v[j] - mu; sq += d * d; }
        red[t] = sq; __syncthreads();
        for (int off = 128; off > 0; off >>= 1) {
            if (t < off) red[t] += red[t + off];
            __syncthreads();
        }
        float rstd = rsqrtf(red[0] * (1.0f / DD) + LN_EPS);
        #pragma unroll
        for (int j = 0; j < 4; ++j) {
            int d = t + j * 256;
            hnorm[b * DD + d] = (v[j] - mu) * rstd * g[d] + bta[d];
        }
        return;
    }
    int pb = b - BB;
    if (pb < 2048) {
        int idx4 = (pb * 256 + t) * 4;
        int i = idx4 >> 10;
        int k = idx4 & 1023;
        const float* src = x + ((size_t)(i >> 6) * TT + 1 + (i & 63)) * DD + k;
        float4 v = *(const float4*)src;
        ushort4 o;
        o.x = f32_to_h16(v.x); o.y = f32_to_h16(v.y);
        o.z = f32_to_h16(v.z); o.w = f32_to_h16(v.w);
        *(ushort4*)&nodesH[idx4] = o;
    } else {
        int q = pb - 2048;
        float (*tile)[33] = (float(*)[33])smem;
        int tx = t & 31;
        int ty = t >> 5;
        int n0 = (q & 31) * 32;
        int kg0 = (q >> 5) * 32;
        #pragma unroll
        for (int j = 0; j < 4; ++j) {
            int r = ty * 4 + j;
            tile[r][tx] = Wf1[(size_t)(kg0 + r) * DD + n0 + tx];
        }
        __syncthreads();
        int half = kg0 >> 10;
        int kk0 = kg0 & 1023;
        unsigned short* o = Wf1T + (size_t)half * DD * DD;
        #pragma unroll
        for (int j = 0; j < 4; ++j) {
            int rn = ty * 4 + j;
            o[(size_t)(n0 + rn) * DD + kk0 + tx] = f32_to_h16(tile[tx][rn]);
        }
    }
}

// ---------------- K2: MFMA (f16) pgemm (blocks 0..255, 512 thr = 8 waves) +
//                      energy1 split-K GEMM (blocks 256..319)
__global__ __launch_bounds__(512) void k2_gemm_kernel(
    const unsigned short* __restrict__ nodesH,
    const unsigned short* __restrict__ Wf1T, const float* __restrict__ bf1,
    unsigned short* __restrict__ P, const float* __restrict__ hnorm,
    const float* __restrict__ We1, float* __restrict__ He) {
    __shared__ unsigned short smem[2 * 128 * 64];  // 32 KB
    int t = threadIdx.x;
    int b = blockIdx.x;
    if (b < 256) {
        unsigned short* As = smem;            // [n-row][k] XOR-swizzled chunks
        unsigned short* Bs = smem + 128 * 64; // [i-row][k]
        int w = t >> 6;
        int lane = t & 63;
        int quad = lane >> 4;
        int l16 = lane & 15;
        int wn = (w & 3) * 32;
        int wi = (w >> 2) * 64;
        int n0 = (b & 7) * 128;
        int i0 = ((b >> 3) & 15) * 128;
        int half = b >> 7;

        const unsigned short* Ag = Wf1T + (size_t)half * DD * DD;
        const unsigned short* Bg = nodesH;

        int sr = lane >> 3;
        int sc = (lane & 7) ^ sr;
        size_t aoff[2], boff[2];
        #pragma unroll
        for (int j = 0; j < 2; ++j) {
            int row = w * 16 + j * 8;
            aoff[j] = (size_t)(n0 + row + sr) * DD + sc * 8;
            boff[j] = (size_t)(i0 + row + sr) * DD + sc * 8;
        }

        floatx4 acc[2][4];
        #pragma unroll
        for (int a = 0; a < 2; ++a)
            #pragma unroll
            for (int c = 0; c < 4; ++c) {
                acc[a][c][0] = 0.f; acc[a][c][1] = 0.f;
                acc[a][c][2] = 0.f; acc[a][c][3] = 0.f;
            }

        for (int k0 = 0; k0 < DD; k0 += 64) {
            #pragma unroll
            for (int j = 0; j < 2; ++j) {
                int row = w * 16 + j * 8;
                load_lds16(Ag + aoff[j] + k0, (void*)(As + row * 64));
                load_lds16(Bg + boff[j] + k0, (void*)(Bs + row * 64));
            }
            __syncthreads();
            #pragma unroll
            for (int s = 0; s < 2; ++s) {
                halfx8 af[2], bfr[4];
                #pragma unroll
                for (int f = 0; f < 2; ++f) {
                    int rn = wn + f * 16 + l16;
                    af[f] = *(const halfx8*)&As[rn * 64 + ((((s << 2) | quad) ^ (rn & 7)) << 3)];
                }
                #pragma unroll
                for (int f = 0; f < 4; ++f) {
                    int ri = wi + f * 16 + l16;
                    bfr[f] = *(const halfx8*)&Bs[ri * 64 + ((((s << 2) | quad) ^ (ri & 7)) << 3)];
                }
                #pragma unroll
                for (int fa = 0; fa < 2; ++fa)
                    #pragma unroll
                    for (int fb = 0; fb < 4; ++fb)
                        acc[fa][fb] = __builtin_amdgcn_mfma_f32_16x16x32_f16(
                            af[fa], bfr[fb], acc[fa][fb], 0, 0, 0);
            }
            __syncthreads();
        }

        unsigned short* Pout = P + (size_t)half * NNODES * DD;
        #pragma unroll
        for (int fa = 0; fa < 2; ++fa) {
            int n = n0 + wn + fa * 16 + quad * 4;
            float4 badd = make_float4(0.f, 0.f, 0.f, 0.f);
            if (half == 0) badd = *(const float4*)(bf1 + n);
            #pragma unroll
            for (int fb = 0; fb < 4; ++fb) {
                int i = i0 + wi + fb * 16 + l16;
                floatx4 v = acc[fa][fb];
                ushort4 o;
                o.x = f32_to_h16(v[0] + badd.x);
                o.y = f32_to_h16(v[1] + badd.y);
                o.z = f32_to_h16(v[2] + badd.z);
                o.w = f32_to_h16(v[3] + badd.w);
                *(ushort4*)&Pout[(size_t)i * DD + n] = o;
            }
        }
        return;
    }
    // energy1: He[ks][r0+r][col] = sum_{64k chunk} h[r][k]*We1[k][col]
    {
        int q = b - 256;
        float* hs = (float*)smem;  // [k][r] 64x16
        int col = (q & 1) * 512 + t;
        int k0 = ((q >> 1) & 15) * 64;
        int r0 = (q >> 5) * 16;
        for (int idx = t; idx < 64 * 16; idx += 512) {
            int r = idx & 15, k = idx >> 4;
            hs[idx] = hnorm[(size_t)(r0 + r) * DD + k0 + k];
        }
        __syncthreads();
        float acc[16];
        #pragma unroll
        for (int r = 0; r < 16; ++r) acc[r] = 0.0f;
        #pragma unroll 4
        for (int k = 0; k < 64; ++k) {
            float wv = We1[(size_t)(k0 + k) * DD + col];
            const float* hrow = hs + k * 16;
            #pragma unroll
            for (int j = 0; j < 4; ++j) {
                float4 h4 = *(const float4*)(hrow + j * 4);
                acc[j * 4 + 0] = fmaf(h4.x, wv, acc[j * 4 + 0]);
                acc[j * 4 + 1] = fmaf(h4.y, wv, acc[j * 4 + 1]);
                acc[j * 4 + 2] = fmaf(h4.z, wv, acc[j * 4 + 2]);
                acc[j * 4 + 3] = fmaf(h4.w, wv, acc[j * 4 + 3]);
            }
        }
        float* o = He + (size_t)((q >> 1) & 15) * 32 * DD;
        #pragma unroll
        for (int r = 0; r < 16; ++r) o[(size_t)(r0 + r) * DD + col] = acc[r];
    }
}

// ---------------- K3: edge kernel (blocks 0..4095) + energy2 (4096..4127)
// Edge path via async LDS gathers: each wave issues all 16 row-segment
// global_load_lds (width 16, zero VGPR buffers), one explicit vmcnt(0) drain,
// then computes 4 edges out of LDS (ds_read_b128 + packed half2 math).
// LDS 64 KB/block -> 2 blocks/CU, 2 waves/SIMD alternating wait<->compute.
__global__ __launch_bounds__(256) void k3_edge_energy2_kernel(
    const unsigned short* __restrict__ P, const int* __restrict__ edge_index,
    const float* __restrict__ evec, const float* __restrict__ edist,
    const float* __restrict__ Wf2, const float* __restrict__ bf2,
    const float* __restrict__ He, const float* __restrict__ be1,
    const float* __restrict__ We2, const float* __restrict__ be2,
    float* __restrict__ out) {
    __shared__ unsigned short elds[32768];  // 64 KB: [wave][edge][row][1024]
    int t = threadIdx.x;
    int b = blockIdx.x;
    if (b < 4096) {
        float* forces = out + BB;
        int lane = t & 63;
        int w = t >> 6;
        int wv = b * 4 + w;  // 0..16383
        int dbase = lane * 8;
        // Wf2 lane slice as 8 half2 (16 elements: 2 segments x 8)
        __half2 wh[8];
        #pragma unroll
        for (int s = 0; s < 2; ++s) {
            float4 a = *(const float4*)(Wf2 + s * 512 + dbase);
            float4 c = *(const float4*)(Wf2 + s * 512 + dbase + 4);
            wh[s * 4 + 0] = __floats2half2_rn(a.x, a.y);
            wh[s * 4 + 1] = __floats2half2_rn(a.z, a.w);
            wh[s * 4 + 2] = __floats2half2_rn(c.x, c.y);
            wh[s * 4 + 3] = __floats2half2_rn(c.z, c.w);
        }
        float bias2 = bf2[0];
        const unsigned short* P1 = P + (size_t)NNODES * DD;

        int i0v[4], i1v[4];
        #pragma unroll
        for (int j = 0; j < 4; ++j) {
            int e = wv + j * 16384;
            i0v[j] = __builtin_amdgcn_readfirstlane(edge_index[e]);
            i1v[j] = __builtin_amdgcn_readfirstlane(edge_index[EE + e]);
        }

        // issue all 16 async gathers: src = per-lane slice, dst = uniform base
        // (+ lane*16 applied by HW). Layout: wbase + edge*2048 + row*1024 + seg*512.
        unsigned short* wbase = elds + w * 8192;
        #pragma unroll
        for (int j = 0; j < 4; ++j) {
            const unsigned short* p0 = P  + (size_t)i0v[j] * DD + dbase;
            const unsigned short* p1 = P1 + (size_t)i1v[j] * DD + dbase;
            #pragma unroll
            for (int s = 0; s < 2; ++s) {
                load_lds16(p0 + s * 512, (void*)(wbase + j * 2048 + s * 512));
                load_lds16(p1 + s * 512, (void*)(wbase + j * 2048 + 1024 + s * 512));
            }
        }
        // single drain for the whole batch; memory clobber pins LDS reads after
        asm volatile("s_waitcnt vmcnt(0)" ::: "memory");

        float accs[2];
        #pragma unroll
        for (int j = 0; j < 4; ++j) {
            const unsigned short* e0 = wbase + j * 2048;
            float acc = 0.0f;
            #pragma unroll
            for (int s = 0; s < 2; ++s) {
                float4 v0 = *(const float4*)(e0 + s * 512 + dbase);
                float4 v1 = *(const float4*)(e0 + 1024 + s * 512 + dbase);
                const __half2* h0 = (const __half2*)&v0;
                const __half2* h1 = (const __half2*)&v1;
                #pragma unroll
                for (int jj = 0; jj < 4; ++jj) {
                    __half2 hv = __hadd2(h0[jj], h1[jj]);
                    acc = dot2f(gelu_h2(hv), wh[s * 4 + jj], acc);
                }
            }
            accs[j & 1] = acc;
            if (j & 1) {
                float a0 = accs[0], a1 = accs[1];
                a0 += __shfl_xor(a0, 32, 64);
                a1 += __shfl_xor(a1, 32, 64);
                float r = (lane < 32) ? a0 : a1;
                #pragma unroll
                for (int off = 16; off > 0; off >>= 1) r += __shfl_xor(r, off, 64);
                float fm = r + bias2;
                int l5 = lane & 31;
                if (l5 < 3) {
                    int je = (lane < 32) ? (j - 1) : j;
                    int e = wv + je * 16384;
                    int i0 = (lane < 32) ? i0v[j - 1] : i0v[j];
                    float sc = fm / edist[e];
                    atomicAdd(&forces[i0 * 3 + l5], sc * evec[e * 3 + l5]);
                }
            }
        }
        return;
    }
    // energy2: sum 16 partials, gelu, dot We2 (fp32 path); red reuses elds
    {
        float* red = (float*)elds;
        int bb = b - 4096;
        float p = 0.0f;
        #pragma unroll
        for (int j = 0; j < 4; ++j) {
            int c = t * 4 + j;
            float s = 0.0f;
            #pragma unroll
            for (int ks = 0; ks < 16; ++ks)
                s += He[(size_t)ks * 32 * DD + bb * DD + c];
            s += be1[c];
            p += gelu_fast(s) * We2[c];
        }
        red[t] = p; __syncthreads();
        for (int off = 128; off > 0; off >>= 1) {
            if (t < off) red[t] += red[t + off];
            __syncthreads();
        }
        if (t == 0) out[bb] = red[0] + be2[0];
    }
}

extern "C" void kernel_launch(void* const* d_in, const int* in_sizes, int n_in,
                              void* d_out, int out_size, void* d_ws, size_t ws_size,
                              hipStream_t stream) {
    const float* x    = (const float*)d_in[0];
    const int* edge_index = (const int*)d_in[2];
    const float* evec = (const float*)d_in[3];
    const float* edist = (const float*)d_in[4];
    const float* ln_g = (const float*)d_in[6];
    const float* ln_b = (const float*)d_in[7];
    const float* We1  = (const float*)d_in[8];
    const float* be1  = (const float*)d_in[9];
    const float* We2  = (const float*)d_in[10];
    const float* be2  = (const float*)d_in[11];
    const float* Wf1  = (const float*)d_in[12];
    const float* bf1  = (const float*)d_in[13];
    const float* Wf2  = (const float*)d_in[14];
    const float* bf2  = (const float*)d_in[15];

    float* out = (float*)d_out;  // [0:32] energy, [32:32+6144] forces

    // ws layout:
    // [0, 8MB)          : P fp16 [2][2048][1024]
    // [8MB, 10MB+128KB) : hnorm (128 KB) + He (2 MB)
    // [11MB, 15MB)      : nodesH fp16 [2048][1024]
    // [16MB, 20MB)      : Wf1T  fp16 [2][1024][1024]
    char* wsb = (char*)d_ws;
    unsigned short* P      = (unsigned short*)(wsb);
    float* hnorm           = (float*)(wsb + (8u << 20));
    float* He              = (float*)(wsb + (8u << 20) + (128u << 10));
    unsigned short* nodesH = (unsigned short*)(wsb + (11u << 20));
    unsigned short* Wf1T   = (unsigned short*)(wsb + (16u << 20));

    k1_zero_ln_prep_kernel<<<4128, 256, 0, stream>>>(x, ln_g, ln_b, Wf1, hnorm,
                                                     out, nodesH, Wf1T);
    k2_gemm_kernel<<<320, 512, 0, stream>>>(nodesH, Wf1T, bf1, P, hnorm, We1, He);
    k3_edge_energy2_kernel<<<4128, 256, 0, stream>>>(P, edge_index, evec, edist,
                                                     Wf2, bf2, He, be1, We2, be2,
                                                     out);
}

// Round 11
// 151.549 us; speedup vs baseline: 1.1003x; 1.1003x over previous
//
#include <hip/hip_runtime.h>
#include <hip/hip_fp16.h>
#include <math.h>

#define BB 32
#define TT 256
#define DD 1024
#define NNODES 2048
#define EE 65536
#define LN_EPS 1e-5f

typedef _Float16 halfx8 __attribute__((ext_vector_type(8)));
typedef __attribute__((ext_vector_type(4))) float floatx4;

__device__ __forceinline__ float gelu_fast(float x) {
    // tanh-approx gelu: x - x/(1+exp2(x*(2.302118 + 0.102945*x^2)))
    float x2 = x * x;
    float z = x * fmaf(0.10294456f, x2, 2.30211786f);
    float e = __builtin_amdgcn_exp2f(z);
    float r = __builtin_amdgcn_rcpf(1.0f + e);
    return fmaf(-x, r, x);
}

// packed half2 sigmoid-gelu: x / (1 + exp2(-2.4554669 x))
__device__ __forceinline__ __half2 gelu_h2(__half2 x) {
    const __half2 k = __float2half2_rn(-2.4554669f);
    const __half2 one = __float2half2_rn(1.0f);
    __half2 e = h2exp2(__hmul2(x, k));
    return __hmul2(x, h2rcp(__hadd2(e, one)));
}

__device__ __forceinline__ float dot2f(__half2 a, __half2 b, float c) {
#if __has_builtin(__builtin_amdgcn_fdot2)
    typedef _Float16 v2h __attribute__((ext_vector_type(2)));
    return __builtin_amdgcn_fdot2(*(v2h*)&a, *(v2h*)&b, c, false);
#else
    float2 af = __half22float2(a), bf = __half22float2(b);
    return fmaf(af.x, bf.x, fmaf(af.y, bf.y, c));
#endif
}

__device__ __forceinline__ unsigned short f32_to_h16(float f) {
    return __half_as_ushort(__float2half_rn(f));
}

__device__ __forceinline__ void load_lds16(const void* g, void* l) {
    __builtin_amdgcn_global_load_lds(
        (const __attribute__((address_space(1))) void*)g,
        (__attribute__((address_space(3))) void*)l, 16, 0, 0);
}

// ---------------- K1: zero d_out + LayerNorm (blocks 0..31) + prep (32..4127)
__global__ __launch_bounds__(256) void k1_zero_ln_prep_kernel(
    const float* __restrict__ x, const float* __restrict__ g,
    const float* __restrict__ bta, const float* __restrict__ Wf1,
    float* __restrict__ hnorm, float* __restrict__ out,
    unsigned short* __restrict__ nodesH, unsigned short* __restrict__ Wf1T) {
    __shared__ float smem[32 * 33];
    int t = threadIdx.x;
    int b = blockIdx.x;
    if (b < BB) {
        int zi = b * 256 + t;
        if (zi < BB + NNODES * 3) out[zi] = 0.0f;
        float* red = smem;
        const float* row = x + (size_t)b * TT * DD;
        float v[4];
        float s = 0.0f;
        #pragma unroll
        for (int j = 0; j < 4; ++j) { v[j] = row[t + j * 256]; s += v[j]; }
        red[t] = s; __syncthreads();
        for (int off = 128; off > 0; off >>= 1) {
            if (t < off) red[t] += red[t + off];
            __syncthreads();
        }
        float mu = red[0] * (1.0f / DD);
        __syncthreads();
        float sq = 0.0f;
        #pragma unroll
        for (int j = 0; j < 4; ++j) { float d = v[j] - mu; sq += d * d; }
        red[t] = sq; __syncthreads();
        for (int off = 128; off > 0; off >>= 1) {
            if (t < off) red[t] += red[t + off];
            __syncthreads();
        }
        float rstd = rsqrtf(red[0] * (1.0f / DD) + LN_EPS);
        #pragma unroll
        for (int j = 0; j < 4; ++j) {
            int d = t + j * 256;
            hnorm[b * DD + d] = (v[j] - mu) * rstd * g[d] + bta[d];
        }
        return;
    }
    int pb = b - BB;
    if (pb < 2048) {
        int idx4 = (pb * 256 + t) * 4;
        int i = idx4 >> 10;
        int k = idx4 & 1023;
        const float* src = x + ((size_t)(i >> 6) * TT + 1 + (i & 63)) * DD + k;
        float4 v = *(const float4*)src;
        ushort4 o;
        o.x = f32_to_h16(v.x); o.y = f32_to_h16(v.y);
        o.z = f32_to_h16(v.z); o.w = f32_to_h16(v.w);
        *(ushort4*)&nodesH[idx4] = o;
    } else {
        int q = pb - 2048;
        float (*tile)[33] = (float(*)[33])smem;
        int tx = t & 31;
        int ty = t >> 5;
        int n0 = (q & 31) * 32;
        int kg0 = (q >> 5) * 32;
        #pragma unroll
        for (int j = 0; j < 4; ++j) {
            int r = ty * 4 + j;
            tile[r][tx] = Wf1[(size_t)(kg0 + r) * DD + n0 + tx];
        }
        __syncthreads();
        int half = kg0 >> 10;
        int kk0 = kg0 & 1023;
        unsigned short* o = Wf1T + (size_t)half * DD * DD;
        #pragma unroll
        for (int j = 0; j < 4; ++j) {
            int rn = ty * 4 + j;
            o[(size_t)(n0 + rn) * DD + kk0 + tx] = f32_to_h16(tile[tx][rn]);
        }
    }
}

// ---------------- K2: MFMA (f16) pgemm (blocks 0..255, 512 thr = 8 waves) +
//                      energy1 split-K GEMM (blocks 256..319)
__global__ __launch_bounds__(512) void k2_gemm_kernel(
    const unsigned short* __restrict__ nodesH,
    const unsigned short* __restrict__ Wf1T, const float* __restrict__ bf1,
    unsigned short* __restrict__ P, const float* __restrict__ hnorm,
    const float* __restrict__ We1, float* __restrict__ He) {
    __shared__ unsigned short smem[2 * 128 * 64];  // 32 KB
    int t = threadIdx.x;
    int b = blockIdx.x;
    if (b < 256) {
        unsigned short* As = smem;            // [n-row][k] XOR-swizzled chunks
        unsigned short* Bs = smem + 128 * 64; // [i-row][k]
        int w = t >> 6;
        int lane = t & 63;
        int quad = lane >> 4;
        int l16 = lane & 15;
        int wn = (w & 3) * 32;
        int wi = (w >> 2) * 64;
        int n0 = (b & 7) * 128;
        int i0 = ((b >> 3) & 15) * 128;
        int half = b >> 7;

        const unsigned short* Ag = Wf1T + (size_t)half * DD * DD;
        const unsigned short* Bg = nodesH;

        int sr = lane >> 3;
        int sc = (lane & 7) ^ sr;
        size_t aoff[2], boff[2];
        #pragma unroll
        for (int j = 0; j < 2; ++j) {
            int row = w * 16 + j * 8;
            aoff[j] = (size_t)(n0 + row + sr) * DD + sc * 8;
            boff[j] = (size_t)(i0 + row + sr) * DD + sc * 8;
        }

        floatx4 acc[2][4];
        #pragma unroll
        for (int a = 0; a < 2; ++a)
            #pragma unroll
            for (int c = 0; c < 4; ++c) {
                acc[a][c][0] = 0.f; acc[a][c][1] = 0.f;
                acc[a][c][2] = 0.f; acc[a][c][3] = 0.f;
            }

        for (int k0 = 0; k0 < DD; k0 += 64) {
            #pragma unroll
            for (int j = 0; j < 2; ++j) {
                int row = w * 16 + j * 8;
                load_lds16(Ag + aoff[j] + k0, (void*)(As + row * 64));
                load_lds16(Bg + boff[j] + k0, (void*)(Bs + row * 64));
            }
            __syncthreads();
            #pragma unroll
            for (int s = 0; s < 2; ++s) {
                halfx8 af[2], bfr[4];
                #pragma unroll
                for (int f = 0; f < 2; ++f) {
                    int rn = wn + f * 16 + l16;
                    af[f] = *(const halfx8*)&As[rn * 64 + ((((s << 2) | quad) ^ (rn & 7)) << 3)];
                }
                #pragma unroll
                for (int f = 0; f < 4; ++f) {
                    int ri = wi + f * 16 + l16;
                    bfr[f] = *(const halfx8*)&Bs[ri * 64 + ((((s << 2) | quad) ^ (ri & 7)) << 3)];
                }
                #pragma unroll
                for (int fa = 0; fa < 2; ++fa)
                    #pragma unroll
                    for (int fb = 0; fb < 4; ++fb)
                        acc[fa][fb] = __builtin_amdgcn_mfma_f32_16x16x32_f16(
                            af[fa], bfr[fb], acc[fa][fb], 0, 0, 0);
            }
            __syncthreads();
        }

        unsigned short* Pout = P + (size_t)half * NNODES * DD;
        #pragma unroll
        for (int fa = 0; fa < 2; ++fa) {
            int n = n0 + wn + fa * 16 + quad * 4;
            float4 badd = make_float4(0.f, 0.f, 0.f, 0.f);
            if (half == 0) badd = *(const float4*)(bf1 + n);
            #pragma unroll
            for (int fb = 0; fb < 4; ++fb) {
                int i = i0 + wi + fb * 16 + l16;
                floatx4 v = acc[fa][fb];
                ushort4 o;
                o.x = f32_to_h16(v[0] + badd.x);
                o.y = f32_to_h16(v[1] + badd.y);
                o.z = f32_to_h16(v[2] + badd.z);
                o.w = f32_to_h16(v[3] + badd.w);
                *(ushort4*)&Pout[(size_t)i * DD + n] = o;
            }
        }
        return;
    }
    // energy1: He[ks][r0+r][col] = sum_{64k chunk} h[r][k]*We1[k][col]
    {
        int q = b - 256;
        float* hs = (float*)smem;  // [k][r] 64x16
        int col = (q & 1) * 512 + t;
        int k0 = ((q >> 1) & 15) * 64;
        int r0 = (q >> 5) * 16;
        for (int idx = t; idx < 64 * 16; idx += 512) {
            int r = idx & 15, k = idx >> 4;
            hs[idx] = hnorm[(size_t)(r0 + r) * DD + k0 + k];
        }
        __syncthreads();
        float acc[16];
        #pragma unroll
        for (int r = 0; r < 16; ++r) acc[r] = 0.0f;
        #pragma unroll 4
        for (int k = 0; k < 64; ++k) {
            float wv = We1[(size_t)(k0 + k) * DD + col];
            const float* hrow = hs + k * 16;
            #pragma unroll
            for (int j = 0; j < 4; ++j) {
                float4 h4 = *(const float4*)(hrow + j * 4);
                acc[j * 4 + 0] = fmaf(h4.x, wv, acc[j * 4 + 0]);
                acc[j * 4 + 1] = fmaf(h4.y, wv, acc[j * 4 + 1]);
                acc[j * 4 + 2] = fmaf(h4.z, wv, acc[j * 4 + 2]);
                acc[j * 4 + 3] = fmaf(h4.w, wv, acc[j * 4 + 3]);
            }
        }
        float* o = He + (size_t)((q >> 1) & 15) * 32 * DD;
        #pragma unroll
        for (int r = 0; r < 16; ++r) o[(size_t)(r0 + r) * DD + col] = acc[r];
    }
}

// ---------------- K3: edge kernel (blocks 0..4095) + energy2 (4096..4127)
// Edge math in packed half2 with fdot2 accumulation; 4 edges per wave with
// one-edge-ahead register double buffer. (LLC-BW-bound at ~6-7 TB/s for the
// 256 MB random row gather -- schedule variants R7-R10 all confirm.)
__global__ __launch_bounds__(256) void k3_edge_energy2_kernel(
    const unsigned short* __restrict__ P, const int* __restrict__ edge_index,
    const float* __restrict__ evec, const float* __restrict__ edist,
    const float* __restrict__ Wf2, const float* __restrict__ bf2,
    const float* __restrict__ He, const float* __restrict__ be1,
    const float* __restrict__ We2, const float* __restrict__ be2,
    float* __restrict__ out) {
    __shared__ float red[256];
    int t = threadIdx.x;
    int b = blockIdx.x;
    if (b < 4096) {
        float* forces = out + BB;
        int lane = t & 63;
        int wv = b * 4 + (t >> 6);  // 0..16383
        int dbase = lane * 8;
        // Wf2 lane slice as 8 half2 (16 elements: 2 segments x 8)
        __half2 wh[8];
        #pragma unroll
        for (int s = 0; s < 2; ++s) {
            float4 a = *(const float4*)(Wf2 + s * 512 + dbase);
            float4 c = *(const float4*)(Wf2 + s * 512 + dbase + 4);
            wh[s * 4 + 0] = __floats2half2_rn(a.x, a.y);
            wh[s * 4 + 1] = __floats2half2_rn(a.z, a.w);
            wh[s * 4 + 2] = __floats2half2_rn(c.x, c.y);
            wh[s * 4 + 3] = __floats2half2_rn(c.z, c.w);
        }
        float bias2 = bf2[0];
        const unsigned short* P1 = P + (size_t)NNODES * DD;

        int i0v[4], i1v[4];
        #pragma unroll
        for (int j = 0; j < 4; ++j) {
            int e = wv + j * 16384;
            i0v[j] = __builtin_amdgcn_readfirstlane(edge_index[e]);
            i1v[j] = __builtin_amdgcn_readfirstlane(edge_index[EE + e]);
        }

        // stage buffers: [buf][0..1] = p0 seg0/1, [2..3] = p1 seg0/1 (16B each)
        float4 buf[2][4];
        #pragma unroll
        for (int s = 0; s < 2; ++s) {
            buf[0][0 + s] = *(const float4*)(P  + (size_t)i0v[0] * DD + dbase + s * 512);
            buf[0][2 + s] = *(const float4*)(P1 + (size_t)i1v[0] * DD + dbase + s * 512);
        }
        float accs[2];
        #pragma unroll
        for (int j = 0; j < 4; ++j) {
            if (j < 3) {
                float4* nb = buf[(j + 1) & 1];
                #pragma unroll
                for (int s = 0; s < 2; ++s) {
                    nb[0 + s] = *(const float4*)(P  + (size_t)i0v[j + 1] * DD + dbase + s * 512);
                    nb[2 + s] = *(const float4*)(P1 + (size_t)i1v[j + 1] * DD + dbase + s * 512);
                }
            }
            const float4* cb = buf[j & 1];
            float acc = 0.0f;
            #pragma unroll
            for (int s = 0; s < 2; ++s) {
                const __half2* h0 = (const __half2*)&cb[s];
                const __half2* h1 = (const __half2*)&cb[2 + s];
                #pragma unroll
                for (int jj = 0; jj < 4; ++jj) {
                    __half2 hv = __hadd2(h0[jj], h1[jj]);
                    acc = dot2f(gelu_h2(hv), wh[s * 4 + jj], acc);
                }
            }
            accs[j & 1] = acc;
            if (j & 1) {
                float a0 = accs[0], a1 = accs[1];
                a0 += __shfl_xor(a0, 32, 64);
                a1 += __shfl_xor(a1, 32, 64);
                float r = (lane < 32) ? a0 : a1;
                #pragma unroll
                for (int off = 16; off > 0; off >>= 1) r += __shfl_xor(r, off, 64);
                float fm = r + bias2;
                int l5 = lane & 31;
                if (l5 < 3) {
                    int je = (lane < 32) ? (j - 1) : j;
                    int e = wv + je * 16384;
                    int i0 = (lane < 32) ? i0v[j - 1] : i0v[j];
                    float sc = fm / edist[e];
                    atomicAdd(&forces[i0 * 3 + l5], sc * evec[e * 3 + l5]);
                }
            }
        }
        return;
    }
    // energy2: sum 16 partials, gelu, dot We2 (fp32 path)
    {
        int bb = b - 4096;
        float p = 0.0f;
        #pragma unroll
        for (int j = 0; j < 4; ++j) {
            int c = t * 4 + j;
            float s = 0.0f;
            #pragma unroll
            for (int ks = 0; ks < 16; ++ks)
                s += He[(size_t)ks * 32 * DD + bb * DD + c];
            s += be1[c];
            p += gelu_fast(s) * We2[c];
        }
        red[t] = p; __syncthreads();
        for (int off = 128; off > 0; off >>= 1) {
            if (t < off) red[t] += red[t + off];
            __syncthreads();
        }
        if (t == 0) out[bb] = red[0] + be2[0];
    }
}

extern "C" void kernel_launch(void* const* d_in, const int* in_sizes, int n_in,
                              void* d_out, int out_size, void* d_ws, size_t ws_size,
                              hipStream_t stream) {
    const float* x    = (const float*)d_in[0];
    const int* edge_index = (const int*)d_in[2];
    const float* evec = (const float*)d_in[3];
    const float* edist = (const float*)d_in[4];
    const float* ln_g = (const float*)d_in[6];
    const float* ln_b = (const float*)d_in[7];
    const float* We1  = (const float*)d_in[8];
    const float* be1  = (const float*)d_in[9];
    const float* We2  = (const float*)d_in[10];
    const float* be2  = (const float*)d_in[11];
    const float* Wf1  = (const float*)d_in[12];
    const float* bf1  = (const float*)d_in[13];
    const float* Wf2  = (const float*)d_in[14];
    const float* bf2  = (const float*)d_in[15];

    float* out = (float*)d_out;  // [0:32] energy, [32:32+6144] forces

    // ws layout:
    // [0, 8MB)          : P fp16 [2][2048][1024]
    // [8MB, 10MB+128KB) : hnorm (128 KB) + He (2 MB)
    // [11MB, 15MB)      : nodesH fp16 [2048][1024]
    // [16MB, 20MB)      : Wf1T  fp16 [2][1024][1024]
    char* wsb = (char*)d_ws;
    unsigned short* P      = (unsigned short*)(wsb);
    float* hnorm           = (float*)(wsb + (8u << 20));
    float* He              = (float*)(wsb + (8u << 20) + (128u << 10));
    unsigned short* nodesH = (unsigned short*)(wsb + (11u << 20));
    unsigned short* Wf1T   = (unsigned short*)(wsb + (16u << 20));

    k1_zero_ln_prep_kernel<<<4128, 256, 0, stream>>>(x, ln_g, ln_b, Wf1, hnorm,
                                                     out, nodesH, Wf1T);
    k2_gemm_kernel<<<320, 512, 0, stream>>>(nodesH, Wf1T, bf1, P, hnorm, We1, He);
    k3_edge_energy2_kernel<<<4128, 256, 0, stream>>>(P, edge_index, evec, edist,
                                                     Wf2, bf2, He, be1, We2, be2,
                                                     out);
}